// Round 1
// baseline (1611.852 us; speedup 1.0000x reference)
//
#include <hip/hip_runtime.h>
#include <math.h>

#define BB 4
#define SS 2048
#define DD 512
#define HH 8
#define DHH 64
#define MROWS (BB*SS)

constexpr float SCALE  = 0.044194173824159216f;  // 1/sqrt(512)
constexpr float LN_EPS = 1e-5f;

// ---------------------------------------------------------------------------
// QKV projection: out = x @ W^T + b, written head-split [B,H,S,DH].
// Classic 64x64 LDS-tiled SGEMM, 16x16 threads, 4x4 accum per thread.
// grid (DD/64, MROWS/64, 3), block (16,16)
// ---------------------------------------------------------------------------
__global__ __launch_bounds__(256) void qkv_kernel(
    const float* __restrict__ x,
    const float* __restrict__ wq, const float* __restrict__ bq,
    const float* __restrict__ wk, const float* __restrict__ bk,
    const float* __restrict__ wv, const float* __restrict__ bv,
    float* __restrict__ Qo, float* __restrict__ Ko, float* __restrict__ Vo)
{
    const float* w; const float* bias; float* out;
    if (blockIdx.z == 0)      { w = wq; bias = bq; out = Qo; }
    else if (blockIdx.z == 1) { w = wk; bias = bk; out = Ko; }
    else                      { w = wv; bias = bv; out = Vo; }

    __shared__ float As[64][17];
    __shared__ float Ws[64][17];

    const int tx = threadIdx.x, ty = threadIdx.y;
    const int t  = ty * 16 + tx;
    const int m0 = blockIdx.y * 64;
    const int n0 = blockIdx.x * 64;

    const int lm = t >> 2;           // row 0..63 this thread stages
    const int lk = (t & 3) << 2;     // k offset 0,4,8,12

    float c[4][4] = {};

    for (int k0 = 0; k0 < DD; k0 += 16) {
        float4 av  = *(const float4*)&x[(size_t)(m0 + lm) * DD + k0 + lk];
        float4 wv4 = *(const float4*)&w[(size_t)(n0 + lm) * DD + k0 + lk];
        __syncthreads();  // previous compute done before overwrite
        As[lm][lk+0] = av.x;  As[lm][lk+1] = av.y;  As[lm][lk+2] = av.z;  As[lm][lk+3] = av.w;
        Ws[lm][lk+0] = wv4.x; Ws[lm][lk+1] = wv4.y; Ws[lm][lk+2] = wv4.z; Ws[lm][lk+3] = wv4.w;
        __syncthreads();
        #pragma unroll
        for (int kk = 0; kk < 16; ++kk) {
            float a[4], bv4[4];
            #pragma unroll
            for (int i = 0; i < 4; ++i) a[i]  = As[ty*4+i][kk];
            #pragma unroll
            for (int j = 0; j < 4; ++j) bv4[j] = Ws[tx*4+j][kk];
            #pragma unroll
            for (int i = 0; i < 4; ++i)
                #pragma unroll
                for (int j = 0; j < 4; ++j)
                    c[i][j] += a[i] * bv4[j];
        }
    }

    #pragma unroll
    for (int i = 0; i < 4; ++i) {
        int row = m0 + ty*4 + i;
        int bidx = row >> 11;          // row / SS
        int s    = row & (SS - 1);     // row % SS
        #pragma unroll
        for (int j = 0; j < 4; ++j) {
            int col = n0 + tx*4 + j;
            int h = col >> 6, d = col & 63;
            out[(((size_t)bidx*HH + h) * SS + s) * DHH + d] = c[i][j] + bias[col];
        }
    }
}

// ---------------------------------------------------------------------------
// Output projection + bias + residual: y = ctx @ Wo^T + bo + x   [MROWS, DD]
// ---------------------------------------------------------------------------
__global__ __launch_bounds__(256) void oproj_kernel(
    const float* __restrict__ A, const float* __restrict__ w,
    const float* __restrict__ bias, const float* __restrict__ resid,
    float* __restrict__ out)
{
    __shared__ float As[64][17];
    __shared__ float Ws[64][17];

    const int tx = threadIdx.x, ty = threadIdx.y;
    const int t  = ty * 16 + tx;
    const int m0 = blockIdx.y * 64;
    const int n0 = blockIdx.x * 64;

    const int lm = t >> 2;
    const int lk = (t & 3) << 2;

    float c[4][4] = {};

    for (int k0 = 0; k0 < DD; k0 += 16) {
        float4 av  = *(const float4*)&A[(size_t)(m0 + lm) * DD + k0 + lk];
        float4 wv4 = *(const float4*)&w[(size_t)(n0 + lm) * DD + k0 + lk];
        __syncthreads();
        As[lm][lk+0] = av.x;  As[lm][lk+1] = av.y;  As[lm][lk+2] = av.z;  As[lm][lk+3] = av.w;
        Ws[lm][lk+0] = wv4.x; Ws[lm][lk+1] = wv4.y; Ws[lm][lk+2] = wv4.z; Ws[lm][lk+3] = wv4.w;
        __syncthreads();
        #pragma unroll
        for (int kk = 0; kk < 16; ++kk) {
            float a[4], bv4[4];
            #pragma unroll
            for (int i = 0; i < 4; ++i) a[i]  = As[ty*4+i][kk];
            #pragma unroll
            for (int j = 0; j < 4; ++j) bv4[j] = Ws[tx*4+j][kk];
            #pragma unroll
            for (int i = 0; i < 4; ++i)
                #pragma unroll
                for (int j = 0; j < 4; ++j)
                    c[i][j] += a[i] * bv4[j];
        }
    }

    #pragma unroll
    for (int i = 0; i < 4; ++i) {
        int row = m0 + ty*4 + i;
        #pragma unroll
        for (int j = 0; j < 4; ++j) {
            int col = n0 + tx*4 + j;
            out[(size_t)row * DD + col] = c[i][j] + bias[col] + resid[(size_t)row * DD + col];
        }
    }
}

// ---------------------------------------------------------------------------
// Flash attention: one block per (b, h, 64-row q tile). 256 threads.
// Thread t: row r = t/4, col quad = t%4 (16 output cols each).
// Q (pre-scaled), K swizzled in LDS; V linear. Online softmax, P via shuffles.
// grid (SS/64, HH, BB), block 256
// ---------------------------------------------------------------------------
__global__ __launch_bounds__(256) void attn_kernel(
    const float* __restrict__ Q, const float* __restrict__ K,
    const float* __restrict__ V, float* __restrict__ ctx)
{
    __shared__ float QsF[64*64];
    __shared__ float KsF[64*64];
    __shared__ float VsF[64*64];

    const int t    = threadIdx.x;
    const int qt   = blockIdx.x, h = blockIdx.y, b = blockIdx.z;
    const int r    = t >> 2;        // 0..63
    const int quad = t & 3;
    const int c0   = quad << 4;

    const float* Qg = Q + ((size_t)(b*HH + h) * SS + qt*64) * DHH;
    const float* Kg = K + (size_t)(b*HH + h) * SS * DHH;
    const float* Vg = V + (size_t)(b*HH + h) * SS * DHH;

    // stage Q tile, pre-scaled, float4-chunk XOR swizzle on (row & 15)
    for (int cc = t; cc < 1024; cc += 256) {
        int mrow = cc >> 4, cch = cc & 15;
        float4 v = *(const float4*)&Qg[mrow*DHH + (cch << 2)];
        v.x *= SCALE; v.y *= SCALE; v.z *= SCALE; v.w *= SCALE;
        *(float4*)&QsF[mrow*64 + ((cch ^ (mrow & 15)) << 2)] = v;
    }

    float m = -INFINITY, l = 0.f;
    float acc[16];
    #pragma unroll
    for (int i = 0; i < 16; ++i) acc[i] = 0.f;

    for (int kv = 0; kv < SS/64; ++kv) {
        __syncthreads();  // previous PV done before K/V overwrite (also covers Q stage)
        const float* Kt = Kg + kv*64*DHH;
        const float* Vt = Vg + kv*64*DHH;
        for (int cc = t; cc < 1024; cc += 256) {
            int mrow = cc >> 4, cch = cc & 15;
            *(float4*)&KsF[mrow*64 + ((cch ^ (mrow >> 4)) << 2)] =
                *(const float4*)&Kt[mrow*DHH + (cch << 2)];
            *(float4*)&VsF[cc << 2] = *(const float4*)&Vt[cc << 2];
        }
        __syncthreads();

        // scores: 16 dots of length 64 (row r vs cols c0..c0+15)
        float sc[16];
        #pragma unroll
        for (int jj = 0; jj < 16; ++jj) sc[jj] = 0.f;
        #pragma unroll
        for (int k4 = 0; k4 < 16; ++k4) {
            float4 qv = *(const float4*)&QsF[r*64 + ((k4 ^ (r & 15)) << 2)];
            #pragma unroll
            for (int jj = 0; jj < 16; ++jj) {
                int j = c0 + jj;
                float4 kvv = *(const float4*)&KsF[j*64 + ((k4 ^ quad) << 2)];
                sc[jj] += qv.x*kvv.x + qv.y*kvv.y + qv.z*kvv.z + qv.w*kvv.w;
            }
        }

        // online softmax (per-row state replicated across the 4-lane quad)
        float tmax = sc[0];
        #pragma unroll
        for (int jj = 1; jj < 16; ++jj) tmax = fmaxf(tmax, sc[jj]);
        tmax = fmaxf(tmax, __shfl_xor(tmax, 1));
        tmax = fmaxf(tmax, __shfl_xor(tmax, 2));
        float mnew = fmaxf(m, tmax);
        float corr = __expf(m - mnew);   // first iter: exp(-inf)=0
        float ps[16], psum = 0.f;
        #pragma unroll
        for (int jj = 0; jj < 16; ++jj) { ps[jj] = __expf(sc[jj] - mnew); psum += ps[jj]; }
        psum += __shfl_xor(psum, 1);
        psum += __shfl_xor(psum, 2);
        l = l * corr + psum;
        m = mnew;
        #pragma unroll
        for (int i = 0; i < 16; ++i) acc[i] *= corr;

        // PV: acc[r][c0..c0+15] += sum_j p[r][j] * V[j][c]
        #pragma unroll
        for (int j = 0; j < 64; ++j) {
            float pj = __shfl(ps[j & 15], (t & ~3) | (j >> 4));
            const float* vrow = &VsF[(j << 6) + c0];
            float4 v0 = *(const float4*)&vrow[0];
            float4 v1 = *(const float4*)&vrow[4];
            float4 v2 = *(const float4*)&vrow[8];
            float4 v3 = *(const float4*)&vrow[12];
            acc[0]  += pj*v0.x; acc[1]  += pj*v0.y; acc[2]  += pj*v0.z; acc[3]  += pj*v0.w;
            acc[4]  += pj*v1.x; acc[5]  += pj*v1.y; acc[6]  += pj*v1.z; acc[7]  += pj*v1.w;
            acc[8]  += pj*v2.x; acc[9]  += pj*v2.y; acc[10] += pj*v2.z; acc[11] += pj*v2.w;
            acc[12] += pj*v3.x; acc[13] += pj*v3.y; acc[14] += pj*v3.z; acc[15] += pj*v3.w;
        }
    }

    float rl = 1.f / l;
    float* outp = &ctx[((size_t)b*SS + qt*64 + r) * DD + h*DHH + c0];
    float4 o;
    o.x = acc[0]*rl;  o.y = acc[1]*rl;  o.z = acc[2]*rl;  o.w = acc[3]*rl;  *(float4*)&outp[0]  = o;
    o.x = acc[4]*rl;  o.y = acc[5]*rl;  o.z = acc[6]*rl;  o.w = acc[7]*rl;  *(float4*)&outp[4]  = o;
    o.x = acc[8]*rl;  o.y = acc[9]*rl;  o.z = acc[10]*rl; o.w = acc[11]*rl; *(float4*)&outp[8]  = o;
    o.x = acc[12]*rl; o.y = acc[13]*rl; o.z = acc[14]*rl; o.w = acc[15]*rl; *(float4*)&outp[12] = o;
}

// ---------------------------------------------------------------------------
// Row LayerNorm: out = (y - mean)/sqrt(var+eps) * gamma + beta
// grid MROWS, block 256 (2 elements per thread)
// ---------------------------------------------------------------------------
__global__ __launch_bounds__(256) void ln_kernel(
    const float* __restrict__ y, const float* __restrict__ gamma,
    const float* __restrict__ beta, float* __restrict__ out)
{
    const int row = blockIdx.x;
    const int t = threadIdx.x;
    const float* yr = y + (size_t)row * DD;

    float2 v = *(const float2*)&yr[t*2];
    float s  = v.x + v.y;
    float sq = v.x*v.x + v.y*v.y;
    #pragma unroll
    for (int off = 1; off < 64; off <<= 1) {
        s  += __shfl_xor(s,  off);
        sq += __shfl_xor(sq, off);
    }
    __shared__ float ss[4], ssq[4];
    int wv = t >> 6;
    if ((t & 63) == 0) { ss[wv] = s; ssq[wv] = sq; }
    __syncthreads();
    s  = ss[0] + ss[1] + ss[2] + ss[3];
    sq = ssq[0] + ssq[1] + ssq[2] + ssq[3];

    float mean = s * (1.0f / DD);
    float var  = sq * (1.0f / DD) - mean * mean;
    float rstd = rsqrtf(var + LN_EPS);

    float2 g  = *(const float2*)&gamma[t*2];
    float2 be = *(const float2*)&beta[t*2];
    float2 o;
    o.x = (v.x - mean) * rstd * g.x + be.x;
    o.y = (v.y - mean) * rstd * g.y + be.y;
    *(float2*)&out[(size_t)row * DD + t*2] = o;
}

// ---------------------------------------------------------------------------
extern "C" void kernel_launch(void* const* d_in, const int* in_sizes, int n_in,
                              void* d_out, int out_size, void* d_ws, size_t ws_size,
                              hipStream_t stream)
{
    const float* x     = (const float*)d_in[0];
    const float* wq    = (const float*)d_in[1];
    const float* bq    = (const float*)d_in[2];
    const float* wk    = (const float*)d_in[3];
    const float* bk    = (const float*)d_in[4];
    const float* wv    = (const float*)d_in[5];
    const float* bv    = (const float*)d_in[6];
    const float* wo    = (const float*)d_in[7];
    const float* bo    = (const float*)d_in[8];
    const float* gamma = (const float*)d_in[9];
    const float* beta  = (const float*)d_in[10];

    const size_t NQ = (size_t)BB * HH * SS * DHH;  // 4,194,304 elements
    float* ws   = (float*)d_ws;
    float* Qb   = ws;
    float* Kb   = ws + NQ;
    float* Vb   = ws + 2*NQ;
    float* ctx  = ws + 3*NQ;
    float* ybuf = Qb;  // reuse Q buffer for pre-LN result

    {
        dim3 blk(16,16);
        dim3 grid(DD/64, MROWS/64, 3);
        qkv_kernel<<<grid, blk, 0, stream>>>(x, wq,bq, wk,bk, wv,bv, Qb, Kb, Vb);
    }
    {
        dim3 grid(SS/64, HH, BB);
        attn_kernel<<<grid, 256, 0, stream>>>(Qb, Kb, Vb, ctx);
    }
    {
        dim3 blk(16,16);
        dim3 grid(DD/64, MROWS/64);
        oproj_kernel<<<grid, blk, 0, stream>>>(ctx, wo, bo, x, ybuf);
    }
    {
        ln_kernel<<<MROWS, 256, 0, stream>>>(ybuf, gamma, beta, (float*)d_out);
    }
}

// Round 2
// 442.891 us; speedup vs baseline: 3.6394x; 3.6394x over previous
//
#include <hip/hip_runtime.h>
#include <math.h>

#define BB 4
#define SS 2048
#define DD 512
#define HH 8
#define DHH 64
#define MROWS (BB*SS)

constexpr float SCALE  = 0.044194173824159216f;  // 1/sqrt(512)
constexpr float LN_EPS = 1e-5f;

typedef __attribute__((ext_vector_type(8))) short bf16x8;
typedef __attribute__((ext_vector_type(4))) float f32x4;

__device__ inline ushort f2bf(float f) {
    union { float f; unsigned u; } v; v.f = f;
    unsigned r = (v.u + 0x7FFFu + ((v.u >> 16) & 1u)) >> 16;  // RNE
    return (ushort)r;
}

// ---------------------------------------------------------------------------
// QKV projection (fp32 compute, bf16 out, head-split [B,H,S,DH]; Q pre-scaled)
// grid (DD/64, MROWS/64, 3), block (16,16)
// ---------------------------------------------------------------------------
__global__ __launch_bounds__(256) void qkv_kernel(
    const float* __restrict__ x,
    const float* __restrict__ wq, const float* __restrict__ bq,
    const float* __restrict__ wk, const float* __restrict__ bk,
    const float* __restrict__ wv, const float* __restrict__ bv,
    ushort* __restrict__ Qo, ushort* __restrict__ Ko, ushort* __restrict__ Vo)
{
    const float* w; const float* bias; ushort* out; float scl;
    if (blockIdx.z == 0)      { w = wq; bias = bq; out = Qo; scl = SCALE; }
    else if (blockIdx.z == 1) { w = wk; bias = bk; out = Ko; scl = 1.0f; }
    else                      { w = wv; bias = bv; out = Vo; scl = 1.0f; }

    __shared__ float As[64][17];
    __shared__ float Ws[64][17];

    const int tx = threadIdx.x, ty = threadIdx.y;
    const int t  = ty * 16 + tx;
    const int m0 = blockIdx.y * 64;
    const int n0 = blockIdx.x * 64;

    const int lm = t >> 2;
    const int lk = (t & 3) << 2;

    float c[4][4] = {};

    for (int k0 = 0; k0 < DD; k0 += 16) {
        float4 av  = *(const float4*)&x[(size_t)(m0 + lm) * DD + k0 + lk];
        float4 wv4 = *(const float4*)&w[(size_t)(n0 + lm) * DD + k0 + lk];
        __syncthreads();
        As[lm][lk+0] = av.x;  As[lm][lk+1] = av.y;  As[lm][lk+2] = av.z;  As[lm][lk+3] = av.w;
        Ws[lm][lk+0] = wv4.x; Ws[lm][lk+1] = wv4.y; Ws[lm][lk+2] = wv4.z; Ws[lm][lk+3] = wv4.w;
        __syncthreads();
        #pragma unroll
        for (int kk = 0; kk < 16; ++kk) {
            float a[4], bv4[4];
            #pragma unroll
            for (int i = 0; i < 4; ++i) a[i]  = As[ty*4+i][kk];
            #pragma unroll
            for (int j = 0; j < 4; ++j) bv4[j] = Ws[tx*4+j][kk];
            #pragma unroll
            for (int i = 0; i < 4; ++i)
                #pragma unroll
                for (int j = 0; j < 4; ++j)
                    c[i][j] += a[i] * bv4[j];
        }
    }

    #pragma unroll
    for (int i = 0; i < 4; ++i) {
        int row = m0 + ty*4 + i;
        int bidx = row >> 11;
        int s    = row & (SS - 1);
        #pragma unroll
        for (int j = 0; j < 4; ++j) {
            int col = n0 + tx*4 + j;
            int h = col >> 6, d = col & 63;
            out[(((size_t)bidx*HH + h) * SS + s) * DHH + d] = f2bf((c[i][j] + bias[col]) * scl);
        }
    }
}

// ---------------------------------------------------------------------------
// V transpose: [B,H,S,DH] bf16 -> [B,H,DH,S] bf16
// grid (SS/64, BB*HH), block 256
// ---------------------------------------------------------------------------
__global__ __launch_bounds__(256) void vtrans_kernel(
    const ushort* __restrict__ V, ushort* __restrict__ Vt)
{
    __shared__ ushort Vs[64][72];
    const int bh = blockIdx.y;
    const int s0 = blockIdx.x * 64;
    const int t  = threadIdx.x;

    const ushort* src = V + ((size_t)bh * SS + s0) * DHH;
    #pragma unroll
    for (int i = 0; i < 2; ++i) {
        int cc = t + 256*i;
        int r = cc >> 3, sl = cc & 7;
        *(int4*)&Vs[r][sl*8] = *(const int4*)&src[(size_t)r*DHH + sl*8];
    }
    __syncthreads();

    const int d = t >> 2, i0 = (t & 3) * 16;
    alignas(16) ushort tmp[16];
    #pragma unroll
    for (int i = 0; i < 16; ++i) tmp[i] = Vs[i0 + i][d];
    ushort* dst = Vt + ((size_t)bh * DHH + d) * SS + s0 + i0;
    *(int4*)&dst[0] = *(int4*)&tmp[0];
    *(int4*)&dst[8] = *(int4*)&tmp[8];
}

// ---------------------------------------------------------------------------
// Flash attention, bf16 MFMA 16x16x32.
// Block: 256 thr = 4 waves; wave w owns q rows [qt*64 + w*16, +16).
// S^T = K·Q^T (lane's q = lane&15); PV as O^T = V^T·P^T (same q mapping).
// K/V^T tiles in LDS with 16B-slot XOR swizzle; P via per-wave swizzled LDS.
// grid (SS/64, HH, BB), block 256
// ---------------------------------------------------------------------------
__global__ __launch_bounds__(256) void attn_kernel(
    const ushort* __restrict__ Q, const ushort* __restrict__ K,
    const ushort* __restrict__ Vt, float* __restrict__ ctx)
{
    __shared__ ushort Ks[64*64];      // 8 KB, swizzled
    __shared__ ushort Vts[64*64];     // 8 KB, swizzled (rows = d)
    __shared__ ushort Ps[4][16*64];   // 2 KB/wave, swizzled

    const int t = threadIdx.x;
    const int w = t >> 6, l = t & 63;
    const int g = l >> 4, c = l & 15;
    const int qt = blockIdx.x, h = blockIdx.y, b = blockIdx.z;
    const size_t bh = (size_t)b * HH + h;

    // Q fragments in registers (B operand): lane holds Q[q=c][ch*32 + 8g + j]
    const ushort* Qrow = Q + (bh * SS + (size_t)qt*64 + w*16 + c) * DHH;
    bf16x8 qf0 = *(const bf16x8*)&Qrow[g*8];
    bf16x8 qf1 = *(const bf16x8*)&Qrow[32 + g*8];

    const ushort* Kbase  = K  + bh * SS * DHH;
    const ushort* Vtbase = Vt + bh * DHH * SS;

    f32x4 acc[4] = {};            // [db]: O^T frag, q=c, d = db*16 + 4g + reg
    float m = -INFINITY, lsum = 0.f;

    for (int kv = 0; kv < SS/64; ++kv) {
        __syncthreads();
        const ushort* Kt = Kbase + (size_t)kv * 64 * DHH;
        #pragma unroll
        for (int i = 0; i < 2; ++i) {
            int cc = t + 256*i;
            int r = cc >> 3, sl = cc & 7;
            *(int4*)((char*)Ks + r*128 + ((sl ^ (r & 7)) << 4)) =
                *(const int4*)((const char*)Kt + r*128 + sl*16);
            *(int4*)((char*)Vts + r*128 + ((sl ^ (r & 7)) << 4)) =
                *(const int4*)&Vtbase[(size_t)r*SS + kv*64 + sl*8];
        }
        __syncthreads();

        // ---- S^T = K · Q^T : 4 krow-blocks × K=64 (2 chained MFMA) ----
        f32x4 s[4];
        #pragma unroll
        for (int krb = 0; krb < 4; ++krb) {
            int row = krb*16 + c;
            bf16x8 kf0 = *(const bf16x8*)((const char*)Ks + row*128 + ((g       ^ (row & 7)) << 4));
            bf16x8 kf1 = *(const bf16x8*)((const char*)Ks + row*128 + (((4 + g) ^ (row & 7)) << 4));
            f32x4 z = {0.f, 0.f, 0.f, 0.f};
            z = __builtin_amdgcn_mfma_f32_16x16x32_bf16(kf0, qf0, z, 0, 0, 0);
            z = __builtin_amdgcn_mfma_f32_16x16x32_bf16(kf1, qf1, z, 0, 0, 0);
            s[krb] = z;
        }

        // ---- online softmax: lane's q = c; krow = krb*16 + 4g + reg ----
        float tmax = -INFINITY;
        #pragma unroll
        for (int krb = 0; krb < 4; ++krb)
            #pragma unroll
            for (int rg = 0; rg < 4; ++rg) tmax = fmaxf(tmax, s[krb][rg]);
        tmax = fmaxf(tmax, __shfl_xor(tmax, 16));
        tmax = fmaxf(tmax, __shfl_xor(tmax, 32));
        float mnew = fmaxf(m, tmax);
        float corr = __expf(m - mnew);

        float p[4][4]; float psum = 0.f;
        #pragma unroll
        for (int krb = 0; krb < 4; ++krb)
            #pragma unroll
            for (int rg = 0; rg < 4; ++rg) {
                float e = __expf(s[krb][rg] - mnew);
                p[krb][rg] = e; psum += e;
            }
        psum += __shfl_xor(psum, 16);
        psum += __shfl_xor(psum, 32);
        lsum = lsum * corr + psum;
        m = mnew;
        #pragma unroll
        for (int db = 0; db < 4; ++db) acc[db] *= corr;

        // ---- P -> LDS (bf16, [16 q][64 k], swizzled); wave-local ----
        ushort* Pw = Ps[w];
        #pragma unroll
        for (int krb = 0; krb < 4; ++krb) {
            int k0 = krb*16 + g*4;
            ushort4 pk;
            pk.x = f2bf(p[krb][0]); pk.y = f2bf(p[krb][1]);
            pk.z = f2bf(p[krb][2]); pk.w = f2bf(p[krb][3]);
            *(ushort4*)((char*)Pw + c*128 + ((((k0 >> 3) ^ (c & 7))) << 4) + (k0 & 7)*2) = pk;
        }

        // ---- O^T += V^T · P^T ----
        #pragma unroll
        for (int jch = 0; jch < 2; ++jch) {
            bf16x8 pf = *(const bf16x8*)((const char*)Pw + c*128 + (((jch*4 + g) ^ (c & 7)) << 4));
            #pragma unroll
            for (int db = 0; db < 4; ++db) {
                int row = db*16 + c;
                bf16x8 vf = *(const bf16x8*)((const char*)Vts + row*128 + (((jch*4 + g) ^ (row & 7)) << 4));
                acc[db] = __builtin_amdgcn_mfma_f32_16x16x32_bf16(vf, pf, acc[db], 0, 0, 0);
            }
        }
    }

    const float rl = 1.f / lsum;
    const int qglob = qt*64 + w*16 + c;
    float* outp = &ctx[((size_t)b*SS + qglob) * DD + h*DHH];
    #pragma unroll
    for (int db = 0; db < 4; ++db) {
        float4 o = { acc[db][0]*rl, acc[db][1]*rl, acc[db][2]*rl, acc[db][3]*rl };
        *(float4*)&outp[db*16 + 4*g] = o;
    }
}

// ---------------------------------------------------------------------------
// Output projection + bias + residual (fp32)
// ---------------------------------------------------------------------------
__global__ __launch_bounds__(256) void oproj_kernel(
    const float* __restrict__ A, const float* __restrict__ w,
    const float* __restrict__ bias, const float* __restrict__ resid,
    float* __restrict__ out)
{
    __shared__ float As[64][17];
    __shared__ float Ws[64][17];

    const int tx = threadIdx.x, ty = threadIdx.y;
    const int t  = ty * 16 + tx;
    const int m0 = blockIdx.y * 64;
    const int n0 = blockIdx.x * 64;

    const int lm = t >> 2;
    const int lk = (t & 3) << 2;

    float c[4][4] = {};

    for (int k0 = 0; k0 < DD; k0 += 16) {
        float4 av  = *(const float4*)&A[(size_t)(m0 + lm) * DD + k0 + lk];
        float4 wv4 = *(const float4*)&w[(size_t)(n0 + lm) * DD + k0 + lk];
        __syncthreads();
        As[lm][lk+0] = av.x;  As[lm][lk+1] = av.y;  As[lm][lk+2] = av.z;  As[lm][lk+3] = av.w;
        Ws[lm][lk+0] = wv4.x; Ws[lm][lk+1] = wv4.y; Ws[lm][lk+2] = wv4.z; Ws[lm][lk+3] = wv4.w;
        __syncthreads();
        #pragma unroll
        for (int kk = 0; kk < 16; ++kk) {
            float a[4], bv4[4];
            #pragma unroll
            for (int i = 0; i < 4; ++i) a[i]  = As[ty*4+i][kk];
            #pragma unroll
            for (int j = 0; j < 4; ++j) bv4[j] = Ws[tx*4+j][kk];
            #pragma unroll
            for (int i = 0; i < 4; ++i)
                #pragma unroll
                for (int j = 0; j < 4; ++j)
                    c[i][j] += a[i] * bv4[j];
        }
    }

    #pragma unroll
    for (int i = 0; i < 4; ++i) {
        int row = m0 + ty*4 + i;
        #pragma unroll
        for (int j = 0; j < 4; ++j) {
            int col = n0 + tx*4 + j;
            out[(size_t)row * DD + col] = c[i][j] + bias[col] + resid[(size_t)row * DD + col];
        }
    }
}

// ---------------------------------------------------------------------------
// Row LayerNorm
// ---------------------------------------------------------------------------
__global__ __launch_bounds__(256) void ln_kernel(
    const float* __restrict__ y, const float* __restrict__ gamma,
    const float* __restrict__ beta, float* __restrict__ out)
{
    const int row = blockIdx.x;
    const int t = threadIdx.x;
    const float* yr = y + (size_t)row * DD;

    float2 v = *(const float2*)&yr[t*2];
    float s  = v.x + v.y;
    float sq = v.x*v.x + v.y*v.y;
    #pragma unroll
    for (int off = 1; off < 64; off <<= 1) {
        s  += __shfl_xor(s,  off);
        sq += __shfl_xor(sq, off);
    }
    __shared__ float ss[4], ssq[4];
    int wv = t >> 6;
    if ((t & 63) == 0) { ss[wv] = s; ssq[wv] = sq; }
    __syncthreads();
    s  = ss[0] + ss[1] + ss[2] + ss[3];
    sq = ssq[0] + ssq[1] + ssq[2] + ssq[3];

    float mean = s * (1.0f / DD);
    float var  = sq * (1.0f / DD) - mean * mean;
    float rstd = rsqrtf(var + LN_EPS);

    float2 g  = *(const float2*)&gamma[t*2];
    float2 be = *(const float2*)&beta[t*2];
    float2 o;
    o.x = (v.x - mean) * rstd * g.x + be.x;
    o.y = (v.y - mean) * rstd * g.y + be.y;
    *(float2*)&out[(size_t)row * DD + t*2] = o;
}

// ---------------------------------------------------------------------------
extern "C" void kernel_launch(void* const* d_in, const int* in_sizes, int n_in,
                              void* d_out, int out_size, void* d_ws, size_t ws_size,
                              hipStream_t stream)
{
    const float* x     = (const float*)d_in[0];
    const float* wq    = (const float*)d_in[1];
    const float* bq    = (const float*)d_in[2];
    const float* wk    = (const float*)d_in[3];
    const float* bk    = (const float*)d_in[4];
    const float* wv    = (const float*)d_in[5];
    const float* bv    = (const float*)d_in[6];
    const float* wo    = (const float*)d_in[7];
    const float* bo    = (const float*)d_in[8];
    const float* gamma = (const float*)d_in[9];
    const float* beta  = (const float*)d_in[10];

    const size_t NQ   = (size_t)BB * HH * SS * DHH;   // 4,194,304 elements
    const size_t BF16B = NQ * 2;                       // 8 MB per bf16 buffer
    char* wsb = (char*)d_ws;
    ushort* Qb  = (ushort*)(wsb);
    ushort* Kb  = (ushort*)(wsb + BF16B);
    ushort* Vb  = (ushort*)(wsb + 2*BF16B);
    ushort* Vtb = (ushort*)(wsb + 3*BF16B);
    float*  ctx = (float*)(wsb + 4*BF16B);
    float*  ybuf = (float*)wsb;   // reuse Qb/Kb region after attention

    {
        dim3 blk(16,16);
        dim3 grid(DD/64, MROWS/64, 3);
        qkv_kernel<<<grid, blk, 0, stream>>>(x, wq,bq, wk,bk, wv,bv, Qb, Kb, Vb);
    }
    {
        dim3 grid(SS/64, BB*HH);
        vtrans_kernel<<<grid, 256, 0, stream>>>(Vb, Vtb);
    }
    {
        dim3 grid(SS/64, HH, BB);
        attn_kernel<<<grid, 256, 0, stream>>>(Qb, Kb, Vtb, ctx);
    }
    {
        dim3 blk(16,16);
        dim3 grid(DD/64, MROWS/64);
        oproj_kernel<<<grid, blk, 0, stream>>>(ctx, wo, bo, x, ybuf);
    }
    {
        ln_kernel<<<MROWS, 256, 0, stream>>>(ybuf, gamma, beta, (float*)d_out);
    }
}

// Round 3
// 141.352 us; speedup vs baseline: 11.4031x; 3.1332x over previous
//
#include <hip/hip_runtime.h>
#include <math.h>

#define BB 4
#define SS 2048
#define DD 512
#define HH 8
#define DHH 64
#define MROWS (BB*SS)

constexpr float SCALE  = 0.044194173824159216f;  // 1/sqrt(512)
constexpr float LN_EPS = 1e-5f;

typedef __attribute__((ext_vector_type(8))) short bf16x8;
typedef __attribute__((ext_vector_type(4))) float f32x4;

__device__ inline ushort f2bf(float f) {
    union { float f; unsigned u; } v; v.f = f;
    unsigned r = (v.u + 0x7FFFu + ((v.u >> 16) & 1u)) >> 16;  // RNE
    return (ushort)r;
}

__device__ __forceinline__ void gload16(const void* gsrc, void* lds_dst) {
    __builtin_amdgcn_global_load_lds(
        (const __attribute__((address_space(1))) unsigned int*)gsrc,
        (__attribute__((address_space(3))) unsigned int*)lds_dst,
        16, 0, 0);
}

// ---------------------------------------------------------------------------
// Cast/pack: xb = bf16(x); wb = bf16([wq*S; wk; wv; wo]); biasc = [bq*S, bk, bv]
// grid 2048, block 256
// ---------------------------------------------------------------------------
__global__ __launch_bounds__(256) void cast_kernel(
    const float* __restrict__ x,
    const float* __restrict__ wq, const float* __restrict__ wk,
    const float* __restrict__ wv, const float* __restrict__ wo,
    const float* __restrict__ bq, const float* __restrict__ bk,
    const float* __restrict__ bv,
    ushort* __restrict__ xb, ushort* __restrict__ wb, float* __restrict__ biasc)
{
    const int gid = blockIdx.x * 256 + threadIdx.x;
    if (gid < 1536) {
        float v = gid < 512 ? bq[gid] * SCALE
                : gid < 1024 ? bk[gid - 512] : bv[gid - 1024];
        biasc[gid] = v;
    }
    const int NX4 = (MROWS * DD) / 4;     // 1048576
    const int NW4 = (DD * DD) / 4;        // 65536
    const int total = NX4 + 4 * NW4;      // 1310720
    for (int i = gid; i < total; i += gridDim.x * 256) {
        float4 v; ushort4 o;
        if (i < NX4) {
            v = ((const float4*)x)[i];
            o.x = f2bf(v.x); o.y = f2bf(v.y); o.z = f2bf(v.z); o.w = f2bf(v.w);
            ((ushort4*)xb)[i] = o;
        } else {
            int j = i - NX4;
            int which = j >> 16;
            int off = j & 65535;
            const float4* src = which == 0 ? (const float4*)wq
                              : which == 1 ? (const float4*)wk
                              : which == 2 ? (const float4*)wv : (const float4*)wo;
            v = src[off];
            float scl = which == 0 ? SCALE : 1.0f;
            o.x = f2bf(v.x * scl); o.y = f2bf(v.y * scl);
            o.z = f2bf(v.z * scl); o.w = f2bf(v.w * scl);
            ((ushort4*)wb)[j] = o;
        }
    }
}

// ---------------------------------------------------------------------------
// Shared GEMM-BT machinery: C[128 x 128] = A[128,K] · B[128,K]^T, bf16 MFMA.
// 256 thr = 4 waves (2x2); frag reads conflict-free via slot^(row&7) swizzle,
// sources pre-swizzled so global_load_lds stays linear (rule #21).
// ---------------------------------------------------------------------------
__device__ __forceinline__ void stage_tile(const ushort* __restrict__ g, int k0,
                                           ushort* lbuf, int t)
{
    #pragma unroll
    for (int i = 0; i < 4; ++i) {
        int cc = i * 256 + t;
        int row = cc >> 3, slot = cc & 7;
        gload16(g + row * DD + k0 + ((slot ^ (row & 7)) << 3), lbuf + cc * 8);
    }
}

__device__ __forceinline__ void mma_step(const ushort* Abuf, const ushort* Bbuf,
                                         int wr, int wc, int c, int g,
                                         f32x4 (&acc)[4][4])
{
    bf16x8 af[2][4], bf[2][4];
    #pragma unroll
    for (int kc = 0; kc < 2; ++kc) {
        int sw = ((kc * 4 + g) ^ (c & 7)) << 4;
        #pragma unroll
        for (int mi = 0; mi < 4; ++mi)
            af[kc][mi] = *(const bf16x8*)((const char*)Abuf + (wr*64 + mi*16 + c)*128 + sw);
        #pragma unroll
        for (int ni = 0; ni < 4; ++ni)
            bf[kc][ni] = *(const bf16x8*)((const char*)Bbuf + (wc*64 + ni*16 + c)*128 + sw);
    }
    #pragma unroll
    for (int kc = 0; kc < 2; ++kc)
        #pragma unroll
        for (int mi = 0; mi < 4; ++mi)
            #pragma unroll
            for (int ni = 0; ni < 4; ++ni)
                acc[mi][ni] = __builtin_amdgcn_mfma_f32_16x16x32_bf16(
                    af[kc][mi], bf[kc][ni], acc[mi][ni], 0, 0, 0);
}

// ---------------------------------------------------------------------------
// QKV projection GEMM. grid (12, 64): x = n-block over [wq;wk;wv], y = m-block.
// Epilogue: +bias, bf16, head-split [B,H,S,DH] into Q/K/V.
// ---------------------------------------------------------------------------
__global__ __launch_bounds__(256) void qkv_mm(
    const ushort* __restrict__ xb, const ushort* __restrict__ wb,
    const float* __restrict__ biasc,
    ushort* __restrict__ Qb, ushort* __restrict__ Kb, ushort* __restrict__ Vb)
{
    __shared__ ushort Abuf[128*64];
    __shared__ ushort Bbuf[128*64];
    const int t = threadIdx.x, w = t >> 6, lane = t & 63;
    const int wr = w >> 1, wc = w & 1, c = lane & 15, g = lane >> 4;
    const int nblk = blockIdx.x, mblk = blockIdx.y;

    const ushort* Ag = xb + (size_t)mblk * 128 * DD;
    const ushort* Bg = wb + (size_t)nblk * 128 * DD;

    f32x4 acc[4][4] = {};

    for (int k0 = 0; k0 < DD; k0 += 64) {
        stage_tile(Ag, k0, Abuf, t);
        stage_tile(Bg, k0, Bbuf, t);
        __syncthreads();
        mma_step(Abuf, Bbuf, wr, wc, c, g, acc);
        __syncthreads();
    }

    const int n0 = nblk * 128;
    const int proj = n0 >> 9;
    ushort* outb = proj == 0 ? Qb : (proj == 1 ? Kb : Vb);
    #pragma unroll
    for (int mi = 0; mi < 4; ++mi) {
        int m = mblk*128 + wr*64 + mi*16 + g*4;
        #pragma unroll
        for (int ni = 0; ni < 4; ++ni) {
            int ng = n0 + wc*64 + ni*16 + c;
            float bias = biasc[ng];
            int col = ng & 511, h = col >> 6, d = col & 63;
            #pragma unroll
            for (int rg = 0; rg < 4; ++rg) {
                int mm = m + rg;
                int bi = mm >> 11, s = mm & 2047;
                outb[(((size_t)bi*HH + h)*SS + s)*DHH + d] = f2bf(acc[mi][ni][rg] + bias);
            }
        }
    }
}

// ---------------------------------------------------------------------------
// Output projection GEMM + bias + residual (fp32 out). grid (4, 64).
// ---------------------------------------------------------------------------
__global__ __launch_bounds__(256) void oproj_mm(
    const ushort* __restrict__ ctx, const ushort* __restrict__ wob,
    const float* __restrict__ bo, const float* __restrict__ resid,
    float* __restrict__ out)
{
    __shared__ ushort Abuf[128*64];
    __shared__ ushort Bbuf[128*64];
    const int t = threadIdx.x, w = t >> 6, lane = t & 63;
    const int wr = w >> 1, wc = w & 1, c = lane & 15, g = lane >> 4;
    const int nblk = blockIdx.x, mblk = blockIdx.y;

    const ushort* Ag = ctx + (size_t)mblk * 128 * DD;
    const ushort* Bg = wob + (size_t)nblk * 128 * DD;

    f32x4 acc[4][4] = {};

    for (int k0 = 0; k0 < DD; k0 += 64) {
        stage_tile(Ag, k0, Abuf, t);
        stage_tile(Bg, k0, Bbuf, t);
        __syncthreads();
        mma_step(Abuf, Bbuf, wr, wc, c, g, acc);
        __syncthreads();
    }

    #pragma unroll
    for (int mi = 0; mi < 4; ++mi) {
        int m = mblk*128 + wr*64 + mi*16 + g*4;
        #pragma unroll
        for (int ni = 0; ni < 4; ++ni) {
            int ng = nblk*128 + wc*64 + ni*16 + c;
            float bias = bo[ng];
            #pragma unroll
            for (int rg = 0; rg < 4; ++rg) {
                int mm = m + rg;
                out[(size_t)mm*DD + ng] = acc[mi][ni][rg] + bias + resid[(size_t)mm*DD + ng];
            }
        }
    }
}

// ---------------------------------------------------------------------------
// V transpose: [B,H,S,DH] bf16 -> [B,H,DH,S] bf16. grid (32, 32), block 256
// ---------------------------------------------------------------------------
__global__ __launch_bounds__(256) void vtrans_kernel(
    const ushort* __restrict__ V, ushort* __restrict__ Vt)
{
    __shared__ ushort Vs[64][72];
    const int bh = blockIdx.y;
    const int s0 = blockIdx.x * 64;
    const int t  = threadIdx.x;

    const ushort* src = V + ((size_t)bh * SS + s0) * DHH;
    #pragma unroll
    for (int i = 0; i < 2; ++i) {
        int cc = t + 256*i;
        int r = cc >> 3, sl = cc & 7;
        *(int4*)&Vs[r][sl*8] = *(const int4*)&src[(size_t)r*DHH + sl*8];
    }
    __syncthreads();

    const int d = t >> 2, i0 = (t & 3) * 16;
    alignas(16) ushort tmp[16];
    #pragma unroll
    for (int i = 0; i < 16; ++i) tmp[i] = Vs[i0 + i][d];
    ushort* dst = Vt + ((size_t)bh * DHH + d) * SS + s0 + i0;
    *(int4*)&dst[0] = *(int4*)&tmp[0];
    *(int4*)&dst[8] = *(int4*)&tmp[8];
}

// ---------------------------------------------------------------------------
// Flash attention, bf16 MFMA 16x16x32. ctx out = bf16 [B,S,D].
// grid (32, 8, 4), block 256
// ---------------------------------------------------------------------------
__global__ __launch_bounds__(256) void attn_kernel(
    const ushort* __restrict__ Q, const ushort* __restrict__ K,
    const ushort* __restrict__ Vt, ushort* __restrict__ ctx)
{
    __shared__ ushort Ks[64*64];
    __shared__ ushort Vts[64*64];
    __shared__ ushort Ps[4][16*64];

    const int t = threadIdx.x;
    const int w = t >> 6, l = t & 63;
    const int g = l >> 4, c = l & 15;
    const int qt = blockIdx.x, h = blockIdx.y, b = blockIdx.z;
    const size_t bh = (size_t)b * HH + h;

    const ushort* Qrow = Q + (bh * SS + (size_t)qt*64 + w*16 + c) * DHH;
    bf16x8 qf0 = *(const bf16x8*)&Qrow[g*8];
    bf16x8 qf1 = *(const bf16x8*)&Qrow[32 + g*8];

    const ushort* Kbase  = K  + bh * SS * DHH;
    const ushort* Vtbase = Vt + bh * DHH * SS;

    f32x4 acc[4] = {};
    float m = -INFINITY, lsum = 0.f;

    for (int kv = 0; kv < SS/64; ++kv) {
        __syncthreads();
        const ushort* Kt = Kbase + (size_t)kv * 64 * DHH;
        #pragma unroll
        for (int i = 0; i < 2; ++i) {
            int cc = t + 256*i;
            int r = cc >> 3, sl = cc & 7;
            *(int4*)((char*)Ks + r*128 + ((sl ^ (r & 7)) << 4)) =
                *(const int4*)((const char*)Kt + r*128 + sl*16);
            *(int4*)((char*)Vts + r*128 + ((sl ^ (r & 7)) << 4)) =
                *(const int4*)&Vtbase[(size_t)r*SS + kv*64 + sl*8];
        }
        __syncthreads();

        f32x4 s[4];
        #pragma unroll
        for (int krb = 0; krb < 4; ++krb) {
            int row = krb*16 + c;
            bf16x8 kf0 = *(const bf16x8*)((const char*)Ks + row*128 + ((g       ^ (row & 7)) << 4));
            bf16x8 kf1 = *(const bf16x8*)((const char*)Ks + row*128 + (((4 + g) ^ (row & 7)) << 4));
            f32x4 z = {0.f, 0.f, 0.f, 0.f};
            z = __builtin_amdgcn_mfma_f32_16x16x32_bf16(kf0, qf0, z, 0, 0, 0);
            z = __builtin_amdgcn_mfma_f32_16x16x32_bf16(kf1, qf1, z, 0, 0, 0);
            s[krb] = z;
        }

        float tmax = -INFINITY;
        #pragma unroll
        for (int krb = 0; krb < 4; ++krb)
            #pragma unroll
            for (int rg = 0; rg < 4; ++rg) tmax = fmaxf(tmax, s[krb][rg]);
        tmax = fmaxf(tmax, __shfl_xor(tmax, 16));
        tmax = fmaxf(tmax, __shfl_xor(tmax, 32));
        float mnew = fmaxf(m, tmax);
        float corr = __expf(m - mnew);

        float p[4][4]; float psum = 0.f;
        #pragma unroll
        for (int krb = 0; krb < 4; ++krb)
            #pragma unroll
            for (int rg = 0; rg < 4; ++rg) {
                float e = __expf(s[krb][rg] - mnew);
                p[krb][rg] = e; psum += e;
            }
        psum += __shfl_xor(psum, 16);
        psum += __shfl_xor(psum, 32);
        lsum = lsum * corr + psum;
        m = mnew;
        #pragma unroll
        for (int db = 0; db < 4; ++db) acc[db] *= corr;

        ushort* Pw = Ps[w];
        #pragma unroll
        for (int krb = 0; krb < 4; ++krb) {
            int k0 = krb*16 + g*4;
            ushort4 pk;
            pk.x = f2bf(p[krb][0]); pk.y = f2bf(p[krb][1]);
            pk.z = f2bf(p[krb][2]); pk.w = f2bf(p[krb][3]);
            *(ushort4*)((char*)Pw + c*128 + ((((k0 >> 3) ^ (c & 7))) << 4) + (k0 & 7)*2) = pk;
        }

        #pragma unroll
        for (int jch = 0; jch < 2; ++jch) {
            bf16x8 pf = *(const bf16x8*)((const char*)Pw + c*128 + (((jch*4 + g) ^ (c & 7)) << 4));
            #pragma unroll
            for (int db = 0; db < 4; ++db) {
                int row = db*16 + c;
                bf16x8 vf = *(const bf16x8*)((const char*)Vts + row*128 + (((jch*4 + g) ^ (row & 7)) << 4));
                acc[db] = __builtin_amdgcn_mfma_f32_16x16x32_bf16(vf, pf, acc[db], 0, 0, 0);
            }
        }
    }

    const float rl = 1.f / lsum;
    const int qglob = qt*64 + w*16 + c;
    ushort* outp = ctx + ((size_t)b*SS + qglob) * DD + h*DHH;
    #pragma unroll
    for (int db = 0; db < 4; ++db) {
        ushort4 o = { f2bf(acc[db][0]*rl), f2bf(acc[db][1]*rl),
                      f2bf(acc[db][2]*rl), f2bf(acc[db][3]*rl) };
        *(ushort4*)&outp[db*16 + 4*g] = o;
    }
}

// ---------------------------------------------------------------------------
// Row LayerNorm
// ---------------------------------------------------------------------------
__global__ __launch_bounds__(256) void ln_kernel(
    const float* __restrict__ y, const float* __restrict__ gamma,
    const float* __restrict__ beta, float* __restrict__ out)
{
    const int row = blockIdx.x;
    const int t = threadIdx.x;
    const float* yr = y + (size_t)row * DD;

    float2 v = *(const float2*)&yr[t*2];
    float s  = v.x + v.y;
    float sq = v.x*v.x + v.y*v.y;
    #pragma unroll
    for (int off = 1; off < 64; off <<= 1) {
        s  += __shfl_xor(s,  off);
        sq += __shfl_xor(sq, off);
    }
    __shared__ float ss[4], ssq[4];
    int wv = t >> 6;
    if ((t & 63) == 0) { ss[wv] = s; ssq[wv] = sq; }
    __syncthreads();
    s  = ss[0] + ss[1] + ss[2] + ss[3];
    sq = ssq[0] + ssq[1] + ssq[2] + ssq[3];

    float mean = s * (1.0f / DD);
    float var  = sq * (1.0f / DD) - mean * mean;
    float rstd = rsqrtf(var + LN_EPS);

    float2 g  = *(const float2*)&gamma[t*2];
    float2 be = *(const float2*)&beta[t*2];
    float2 o;
    o.x = (v.x - mean) * rstd * g.x + be.x;
    o.y = (v.y - mean) * rstd * g.y + be.y;
    *(float2*)&out[(size_t)row * DD + t*2] = o;
}

// ---------------------------------------------------------------------------
extern "C" void kernel_launch(void* const* d_in, const int* in_sizes, int n_in,
                              void* d_out, int out_size, void* d_ws, size_t ws_size,
                              hipStream_t stream)
{
    const float* x     = (const float*)d_in[0];
    const float* wq    = (const float*)d_in[1];
    const float* bq    = (const float*)d_in[2];
    const float* wk    = (const float*)d_in[3];
    const float* bk    = (const float*)d_in[4];
    const float* wv    = (const float*)d_in[5];
    const float* bv    = (const float*)d_in[6];
    const float* wo    = (const float*)d_in[7];
    const float* bo    = (const float*)d_in[8];
    const float* gamma = (const float*)d_in[9];
    const float* beta  = (const float*)d_in[10];

    char* wsb = (char*)d_ws;
    const size_t MB = 1u << 20;
    ushort* xb    = (ushort*)(wsb + 0*MB);    // 8 MB; reused as Vtb after qkv
    ushort* wb    = (ushort*)(wsb + 8*MB);    // 2 MB
    float*  biasc = (float* )(wsb + 10*MB);   // 6 KB
    ushort* Qb    = (ushort*)(wsb + 11*MB);   // 8 MB
    ushort* Kb    = (ushort*)(wsb + 19*MB);   // 8 MB
    ushort* Vb    = (ushort*)(wsb + 27*MB);   // 8 MB
    ushort* ctxb  = (ushort*)(wsb + 35*MB);   // 8 MB
    ushort* Vtb   = xb;                        // alias: x dead after qkv_mm
    float*  ybuf  = (float*)(wsb + 11*MB);    // 16 MB over Qb+Kb (dead after attn)

    cast_kernel<<<2048, 256, 0, stream>>>(x, wq, wk, wv, wo, bq, bk, bv,
                                          xb, wb, biasc);
    {
        dim3 grid(12, 64);
        qkv_mm<<<grid, 256, 0, stream>>>(xb, wb, biasc, Qb, Kb, Vb);
    }
    {
        dim3 grid(SS/64, BB*HH);
        vtrans_kernel<<<grid, 256, 0, stream>>>(Vb, Vtb);
    }
    {
        dim3 grid(SS/64, HH, BB);
        attn_kernel<<<grid, 256, 0, stream>>>(Qb, Kb, Vtb, ctxb);
    }
    {
        dim3 grid(4, 64);
        oproj_mm<<<grid, 256, 0, stream>>>(ctxb, wb + 3*DD*DD, bo, x, ybuf);
    }
    ln_kernel<<<MROWS, 256, 0, stream>>>(ybuf, gamma, beta, (float*)d_out);
}

// Round 4
// 131.846 us; speedup vs baseline: 12.2253x; 1.0721x over previous
//
#include <hip/hip_runtime.h>
#include <hip/hip_bf16.h>
#include <math.h>

#define BB 4
#define SS 2048
#define DD 512
#define HH 8
#define DHH 64
#define MROWS (BB*SS)

constexpr float SCALE  = 0.044194173824159216f;            // 1/sqrt(512)
constexpr float QSCALE = (float)(0.044194173824159216 * 1.4426950408889634); // SCALE*log2(e)
constexpr float LN_EPS = 1e-5f;
constexpr float DEFER_THR = 12.0f;                          // log2-domain (~e^8.3)

typedef __attribute__((ext_vector_type(8))) short bf16x8;
typedef __attribute__((ext_vector_type(4))) float f32x4;

__device__ __forceinline__ ushort f2bf(float f) {
    __hip_bfloat16 h = __float2bfloat16(f);   // RNE; compiler pairs into v_cvt_pk_bf16_f32
    ushort u; __builtin_memcpy(&u, &h, 2);
    return u;
}

__device__ __forceinline__ float exp2_hw(float x) {
#if __has_builtin(__builtin_amdgcn_exp2f)
    return __builtin_amdgcn_exp2f(x);
#else
    return exp2f(x);
#endif
}

__device__ __forceinline__ void gload16(const void* gsrc, void* lds_dst) {
    __builtin_amdgcn_global_load_lds(
        (const __attribute__((address_space(1))) unsigned int*)gsrc,
        (__attribute__((address_space(3))) unsigned int*)lds_dst,
        16, 0, 0);
}

// ---------------------------------------------------------------------------
// Cast/pack: xb = bf16(x); wb = bf16([wq*QS; wk; wv; wo]); biasc = [bq*QS, bk, bv]
// grid 2048, block 256
// ---------------------------------------------------------------------------
__global__ __launch_bounds__(256) void cast_kernel(
    const float* __restrict__ x,
    const float* __restrict__ wq, const float* __restrict__ wk,
    const float* __restrict__ wv, const float* __restrict__ wo,
    const float* __restrict__ bq, const float* __restrict__ bk,
    const float* __restrict__ bv,
    ushort* __restrict__ xb, ushort* __restrict__ wb, float* __restrict__ biasc)
{
    const int gid = blockIdx.x * 256 + threadIdx.x;
    if (gid < 1536) {
        float v = gid < 512 ? bq[gid] * QSCALE
                : gid < 1024 ? bk[gid - 512] : bv[gid - 1024];
        biasc[gid] = v;
    }
    const int NX4 = (MROWS * DD) / 4;     // 1048576
    const int NW4 = (DD * DD) / 4;        // 65536
    const int total = NX4 + 4 * NW4;      // 1310720
    for (int i = gid; i < total; i += gridDim.x * 256) {
        float4 v; ushort4 o;
        if (i < NX4) {
            v = ((const float4*)x)[i];
            o.x = f2bf(v.x); o.y = f2bf(v.y); o.z = f2bf(v.z); o.w = f2bf(v.w);
            ((ushort4*)xb)[i] = o;
        } else {
            int j = i - NX4;
            int which = j >> 16;
            int off = j & 65535;
            const float4* src = which == 0 ? (const float4*)wq
                              : which == 1 ? (const float4*)wk
                              : which == 2 ? (const float4*)wv : (const float4*)wo;
            v = src[off];
            float scl = which == 0 ? QSCALE : 1.0f;
            o.x = f2bf(v.x * scl); o.y = f2bf(v.y * scl);
            o.z = f2bf(v.z * scl); o.w = f2bf(v.w * scl);
            ((ushort4*)wb)[j] = o;
        }
    }
}

// ---------------------------------------------------------------------------
// Shared GEMM-BT machinery: C[128 x 128] = A[128,K] · B[128,K]^T, bf16 MFMA.
// ---------------------------------------------------------------------------
__device__ __forceinline__ void stage_tile(const ushort* __restrict__ g, int k0,
                                           ushort* lbuf, int t)
{
    #pragma unroll
    for (int i = 0; i < 4; ++i) {
        int cc = i * 256 + t;
        int row = cc >> 3, slot = cc & 7;
        gload16(g + row * DD + k0 + ((slot ^ (row & 7)) << 3), lbuf + cc * 8);
    }
}

__device__ __forceinline__ void mma_step(const ushort* Abuf, const ushort* Bbuf,
                                         int wr, int wc, int c, int g,
                                         f32x4 (&acc)[4][4])
{
    bf16x8 af[2][4], bf[2][4];
    #pragma unroll
    for (int kc = 0; kc < 2; ++kc) {
        int sw = ((kc * 4 + g) ^ (c & 7)) << 4;
        #pragma unroll
        for (int mi = 0; mi < 4; ++mi)
            af[kc][mi] = *(const bf16x8*)((const char*)Abuf + (wr*64 + mi*16 + c)*128 + sw);
        #pragma unroll
        for (int ni = 0; ni < 4; ++ni)
            bf[kc][ni] = *(const bf16x8*)((const char*)Bbuf + (wc*64 + ni*16 + c)*128 + sw);
    }
    __builtin_amdgcn_s_setprio(1);
    #pragma unroll
    for (int kc = 0; kc < 2; ++kc)
        #pragma unroll
        for (int mi = 0; mi < 4; ++mi)
            #pragma unroll
            for (int ni = 0; ni < 4; ++ni)
                acc[mi][ni] = __builtin_amdgcn_mfma_f32_16x16x32_bf16(
                    af[kc][mi], bf[kc][ni], acc[mi][ni], 0, 0, 0);
    __builtin_amdgcn_s_setprio(0);
}

// ---------------------------------------------------------------------------
// QKV projection GEMM. grid (12, 64). Epilogue: +bias, bf16, head-split
// [B,H,S,DH] for Q/K; V written TRANSPOSED [B,H,DH,S] (vtrans fused away).
// ---------------------------------------------------------------------------
__global__ __launch_bounds__(256) void qkv_mm(
    const ushort* __restrict__ xb, const ushort* __restrict__ wb,
    const float* __restrict__ biasc,
    ushort* __restrict__ Qb, ushort* __restrict__ Kb, ushort* __restrict__ Vtb)
{
    __shared__ ushort Abuf[128*64];
    __shared__ ushort Bbuf[128*64];
    const int t = threadIdx.x, w = t >> 6, lane = t & 63;
    const int wr = w >> 1, wc = w & 1, c = lane & 15, g = lane >> 4;
    const int nblk = blockIdx.x, mblk = blockIdx.y;

    const ushort* Ag = xb + (size_t)mblk * 128 * DD;
    const ushort* Bg = wb + (size_t)nblk * 128 * DD;

    f32x4 acc[4][4] = {};

    for (int k0 = 0; k0 < DD; k0 += 64) {
        stage_tile(Ag, k0, Abuf, t);
        stage_tile(Bg, k0, Bbuf, t);
        __syncthreads();
        mma_step(Abuf, Bbuf, wr, wc, c, g, acc);
        __syncthreads();
    }

    const int n0 = nblk * 128;
    const int proj = n0 >> 9;
    #pragma unroll
    for (int mi = 0; mi < 4; ++mi) {
        int m = mblk*128 + wr*64 + mi*16 + g*4;
        int bi = m >> 11, s = m & 2047;
        #pragma unroll
        for (int ni = 0; ni < 4; ++ni) {
            int ng = n0 + wc*64 + ni*16 + c;
            float bias = biasc[ng];
            int col = ng & 511, h = col >> 6, d = col & 63;
            if (proj == 2) {
                ushort4 o = { f2bf(acc[mi][ni][0] + bias), f2bf(acc[mi][ni][1] + bias),
                              f2bf(acc[mi][ni][2] + bias), f2bf(acc[mi][ni][3] + bias) };
                *(ushort4*)&Vtb[(((size_t)bi*HH + h)*DHH + d)*SS + s] = o;
            } else {
                ushort* outb = proj == 0 ? Qb : Kb;
                #pragma unroll
                for (int rg = 0; rg < 4; ++rg) {
                    outb[(((size_t)bi*HH + h)*SS + (s + rg))*DHH + d] = f2bf(acc[mi][ni][rg] + bias);
                }
            }
        }
    }
}

// ---------------------------------------------------------------------------
// Output projection GEMM + bias + residual (fp32 out). grid (4, 64).
// ---------------------------------------------------------------------------
__global__ __launch_bounds__(256) void oproj_mm(
    const ushort* __restrict__ ctx, const ushort* __restrict__ wob,
    const float* __restrict__ bo, const float* __restrict__ resid,
    float* __restrict__ out)
{
    __shared__ ushort Abuf[128*64];
    __shared__ ushort Bbuf[128*64];
    const int t = threadIdx.x, w = t >> 6, lane = t & 63;
    const int wr = w >> 1, wc = w & 1, c = lane & 15, g = lane >> 4;
    const int nblk = blockIdx.x, mblk = blockIdx.y;

    const ushort* Ag = ctx + (size_t)mblk * 128 * DD;
    const ushort* Bg = wob + (size_t)nblk * 128 * DD;

    f32x4 acc[4][4] = {};

    for (int k0 = 0; k0 < DD; k0 += 64) {
        stage_tile(Ag, k0, Abuf, t);
        stage_tile(Bg, k0, Bbuf, t);
        __syncthreads();
        mma_step(Abuf, Bbuf, wr, wc, c, g, acc);
        __syncthreads();
    }

    #pragma unroll
    for (int mi = 0; mi < 4; ++mi) {
        int m = mblk*128 + wr*64 + mi*16 + g*4;
        #pragma unroll
        for (int ni = 0; ni < 4; ++ni) {
            int ng = nblk*128 + wc*64 + ni*16 + c;
            float bias = bo[ng];
            #pragma unroll
            for (int rg = 0; rg < 4; ++rg) {
                int mm = m + rg;
                out[(size_t)mm*DD + ng] = acc[mi][ni][rg] + bias + resid[(size_t)mm*DD + ng];
            }
        }
    }
}

// ---------------------------------------------------------------------------
// Flash attention, bf16 MFMA 16x16x32, log2-domain softmax, defer-max,
// double-buffered global_load_lds staging. ctx out = bf16 [B,S,D].
// grid (32, 8, 4), block 256
// ---------------------------------------------------------------------------
__global__ __launch_bounds__(256) void attn_kernel(
    const ushort* __restrict__ Q, const ushort* __restrict__ K,
    const ushort* __restrict__ Vt, ushort* __restrict__ ctx)
{
    __shared__ ushort Ks[2][64*64];    // 16 KB
    __shared__ ushort Vts[2][64*64];   // 16 KB
    __shared__ ushort Ps[4][16*64];    //  8 KB

    const int t = threadIdx.x;
    const int w = t >> 6, l = t & 63;
    const int g = l >> 4, c = l & 15;
    const int qt = blockIdx.x, h = blockIdx.y, b = blockIdx.z;
    const size_t bh = (size_t)b * HH + h;

    const ushort* Qrow = Q + (bh * SS + (size_t)qt*64 + w*16 + c) * DHH;
    bf16x8 qf0 = *(const bf16x8*)&Qrow[g*8];
    bf16x8 qf1 = *(const bf16x8*)&Qrow[32 + g*8];

    // staging source offsets (pre-swizzled per rule #21; LDS dst linear)
    const int r1 = t >> 3, sl = t & 7;
    const int r2 = r1 + 32;
    const int ksw1 = r1*DHH + ((sl ^ (r1 & 7)) << 3);
    const int ksw2 = r2*DHH + ((sl ^ (r2 & 7)) << 3);
    const int vsw1 = r1*SS  + ((sl ^ (r1 & 7)) << 3);
    const int vsw2 = r2*SS  + ((sl ^ (r2 & 7)) << 3);
    const ushort* Kbase  = K  + bh * SS * DHH;
    const ushort* Vtbase = Vt + bh * DHH * SS;

#define ATTN_STAGE(kvi, bi_) do {                                   \
        const ushort* kp_ = Kbase  + (size_t)(kvi) * 64 * DHH;      \
        const ushort* vp_ = Vtbase + (kvi) * 64;                    \
        gload16(kp_ + ksw1, &Ks[bi_][t*8]);                         \
        gload16(kp_ + ksw2, &Ks[bi_][(t+256)*8]);                   \
        gload16(vp_ + vsw1, &Vts[bi_][t*8]);                        \
        gload16(vp_ + vsw2, &Vts[bi_][(t+256)*8]);                  \
    } while (0)

    f32x4 acc[4] = {};
    float m = -INFINITY, lsum = 0.f;

    ATTN_STAGE(0, 0);

    for (int kv = 0; kv < SS/64; ++kv) {
        const int cur = kv & 1;
        __syncthreads();                      // drains vmcnt -> tile kv ready
        if (kv + 1 < SS/64) ATTN_STAGE(kv + 1, cur ^ 1);

        const ushort* Kc = Ks[cur];
        const ushort* Vc = Vts[cur];

        // ---- S^T = K · Q^T ----
        f32x4 s[4];
        __builtin_amdgcn_s_setprio(1);
        #pragma unroll
        for (int krb = 0; krb < 4; ++krb) {
            int row = krb*16 + c;
            bf16x8 kf0 = *(const bf16x8*)((const char*)Kc + row*128 + ((g       ^ (row & 7)) << 4));
            bf16x8 kf1 = *(const bf16x8*)((const char*)Kc + row*128 + (((4 + g) ^ (row & 7)) << 4));
            f32x4 z = {0.f, 0.f, 0.f, 0.f};
            z = __builtin_amdgcn_mfma_f32_16x16x32_bf16(kf0, qf0, z, 0, 0, 0);
            z = __builtin_amdgcn_mfma_f32_16x16x32_bf16(kf1, qf1, z, 0, 0, 0);
            s[krb] = z;
        }
        __builtin_amdgcn_s_setprio(0);

        // ---- online softmax (log2 domain), defer-max ----
        float mx01 = fmaxf(fmaxf(s[0][0], s[0][1]), fmaxf(s[0][2], s[0][3]));
        float mx23 = fmaxf(fmaxf(s[1][0], s[1][1]), fmaxf(s[1][2], s[1][3]));
        float mx45 = fmaxf(fmaxf(s[2][0], s[2][1]), fmaxf(s[2][2], s[2][3]));
        float mx67 = fmaxf(fmaxf(s[3][0], s[3][1]), fmaxf(s[3][2], s[3][3]));
        float tmax = fmaxf(fmaxf(mx01, mx23), fmaxf(mx45, mx67));
        tmax = fmaxf(tmax, __shfl_xor(tmax, 16));
        tmax = fmaxf(tmax, __shfl_xor(tmax, 32));

        if (!__all(tmax <= m + DEFER_THR)) {
            float mnew = fmaxf(m, tmax);
            float corr = exp2_hw(m - mnew);
            lsum *= corr;
            #pragma unroll
            for (int db = 0; db < 4; ++db) acc[db] *= corr;
            m = mnew;
        }

        float p[4][4]; float psum = 0.f;
        #pragma unroll
        for (int krb = 0; krb < 4; ++krb)
            #pragma unroll
            for (int rg = 0; rg < 4; ++rg) {
                float e = exp2_hw(s[krb][rg] - m);
                p[krb][rg] = e; psum += e;
            }
        psum += __shfl_xor(psum, 16);
        psum += __shfl_xor(psum, 32);
        lsum += psum;

        // ---- P -> LDS (bf16, swizzled, wave-local) ----
        ushort* Pw = Ps[w];
        #pragma unroll
        for (int krb = 0; krb < 4; ++krb) {
            int k0 = krb*16 + g*4;
            ushort4 pk = { f2bf(p[krb][0]), f2bf(p[krb][1]),
                           f2bf(p[krb][2]), f2bf(p[krb][3]) };
            *(ushort4*)((char*)Pw + c*128 + ((((k0 >> 3) ^ (c & 7))) << 4) + (k0 & 7)*2) = pk;
        }

        // ---- O^T += V^T · P^T ----
        #pragma unroll
        for (int jch = 0; jch < 2; ++jch) {
            bf16x8 pf = *(const bf16x8*)((const char*)Pw + c*128 + (((jch*4 + g) ^ (c & 7)) << 4));
            __builtin_amdgcn_s_setprio(1);
            #pragma unroll
            for (int db = 0; db < 4; ++db) {
                int row = db*16 + c;
                bf16x8 vf = *(const bf16x8*)((const char*)Vc + row*128 + (((jch*4 + g) ^ (row & 7)) << 4));
                acc[db] = __builtin_amdgcn_mfma_f32_16x16x32_bf16(vf, pf, acc[db], 0, 0, 0);
            }
            __builtin_amdgcn_s_setprio(0);
        }
    }
#undef ATTN_STAGE

    const float rl = 1.f / lsum;
    const int qglob = qt*64 + w*16 + c;
    ushort* outp = ctx + ((size_t)b*SS + qglob) * DD + h*DHH;
    #pragma unroll
    for (int db = 0; db < 4; ++db) {
        ushort4 o = { f2bf(acc[db][0]*rl), f2bf(acc[db][1]*rl),
                      f2bf(acc[db][2]*rl), f2bf(acc[db][3]*rl) };
        *(ushort4*)&outp[db*16 + 4*g] = o;
    }
}

// ---------------------------------------------------------------------------
// Row LayerNorm
// ---------------------------------------------------------------------------
__global__ __launch_bounds__(256) void ln_kernel(
    const float* __restrict__ y, const float* __restrict__ gamma,
    const float* __restrict__ beta, float* __restrict__ out)
{
    const int row = blockIdx.x;
    const int t = threadIdx.x;
    const float* yr = y + (size_t)row * DD;

    float2 v = *(const float2*)&yr[t*2];
    float s  = v.x + v.y;
    float sq = v.x*v.x + v.y*v.y;
    #pragma unroll
    for (int off = 1; off < 64; off <<= 1) {
        s  += __shfl_xor(s,  off);
        sq += __shfl_xor(sq, off);
    }
    __shared__ float ss[4], ssq[4];
    int wv = t >> 6;
    if ((t & 63) == 0) { ss[wv] = s; ssq[wv] = sq; }
    __syncthreads();
    s  = ss[0] + ss[1] + ss[2] + ss[3];
    sq = ssq[0] + ssq[1] + ssq[2] + ssq[3];

    float mean = s * (1.0f / DD);
    float var  = sq * (1.0f / DD) - mean * mean;
    float rstd = rsqrtf(var + LN_EPS);

    float2 g  = *(const float2*)&gamma[t*2];
    float2 be = *(const float2*)&beta[t*2];
    float2 o;
    o.x = (v.x - mean) * rstd * g.x + be.x;
    o.y = (v.y - mean) * rstd * g.y + be.y;
    *(float2*)&out[(size_t)row * DD + t*2] = o;
}

// ---------------------------------------------------------------------------
extern "C" void kernel_launch(void* const* d_in, const int* in_sizes, int n_in,
                              void* d_out, int out_size, void* d_ws, size_t ws_size,
                              hipStream_t stream)
{
    const float* x     = (const float*)d_in[0];
    const float* wq    = (const float*)d_in[1];
    const float* bq    = (const float*)d_in[2];
    const float* wk    = (const float*)d_in[3];
    const float* bk    = (const float*)d_in[4];
    const float* wv    = (const float*)d_in[5];
    const float* bv    = (const float*)d_in[6];
    const float* wo    = (const float*)d_in[7];
    const float* bo    = (const float*)d_in[8];
    const float* gamma = (const float*)d_in[9];
    const float* beta  = (const float*)d_in[10];

    char* wsb = (char*)d_ws;
    const size_t MB = 1u << 20;
    ushort* xb    = (ushort*)(wsb + 0*MB);    // 8 MB
    ushort* wb    = (ushort*)(wsb + 8*MB);    // 2 MB
    float*  biasc = (float* )(wsb + 10*MB);   // 6 KB
    ushort* Qb    = (ushort*)(wsb + 11*MB);   // 8 MB
    ushort* Kb    = (ushort*)(wsb + 19*MB);   // 8 MB
    ushort* Vtb   = (ushort*)(wsb + 27*MB);   // 8 MB (transposed V, from qkv_mm)
    ushort* ctxb  = (ushort*)(wsb + 35*MB);   // 8 MB
    float*  ybuf  = (float*)(wsb + 11*MB);    // 16 MB over Qb+Kb (dead after attn)

    cast_kernel<<<2048, 256, 0, stream>>>(x, wq, wk, wv, wo, bq, bk, bv,
                                          xb, wb, biasc);
    {
        dim3 grid(12, 64);
        qkv_mm<<<grid, 256, 0, stream>>>(xb, wb, biasc, Qb, Kb, Vtb);
    }
    {
        dim3 grid(SS/64, HH, BB);
        attn_kernel<<<grid, 256, 0, stream>>>(Qb, Kb, Vtb, ctxb);
    }
    {
        dim3 grid(4, 64);
        oproj_mm<<<grid, 256, 0, stream>>>(ctxb, wb + 3*DD*DD, bo, x, ybuf);
    }
    ln_kernel<<<MROWS, 256, 0, stream>>>(ybuf, gamma, beta, (float*)d_out);
}